// Round 7
// baseline (1227.271 us; speedup 1.0000x reference)
//
#include <hip/hip_runtime.h>
#include <math.h>

#define BN 32768
#define DN 256
#define KN 8192
#define CCAP 20

// Output layout (floats, concatenated in reference return order)
#define O_LOSS 8388608       // BN*DN
#define O_IDX  8388609
#define O_PERP 8421377       // O_IDX + BN
#define O_EMB  8421378
#define O_CS   10518530      // O_EMB + KN*DN
#define O_ES   10526722      // O_CS + KN

typedef _Float16 half_t;
typedef __attribute__((ext_vector_type(4))) _Float16 half4v;
typedef __attribute__((ext_vector_type(8))) _Float16 half8;
typedef __attribute__((ext_vector_type(16))) float float16v;
typedef unsigned long long u64;
typedef unsigned int u32;

__device__ __forceinline__ float wave_reduce_add(float v) {
#pragma unroll
  for (int off = 32; off > 0; off >>= 1) v += __shfl_down(v, off);
  return v;
}

__device__ __forceinline__ u32 enc_f(float d) {
  u32 fb = __float_as_uint(d);
  return fb ^ ((fb >> 31) ? 0xFFFFFFFFu : 0x80000000u);
}

// pack z hi-half into [ztile128][kg32][row%128][8] + hi/lo norms per row
__global__ __launch_bounds__(256) void k_prep_z(const float* __restrict__ z,
                                                half_t* __restrict__ zh,
                                                float* __restrict__ znh,
                                                float* __restrict__ znl) {
  const int wid = threadIdx.x >> 6, lane = threadIdx.x & 63;
  const int row = blockIdx.x * 4 + wid;
  float4 v = *(const float4*)(z + (size_t)row * DN + lane * 4);
  float xs[4] = {v.x, v.y, v.z, v.w};
  half4v hv;
  float h2 = 0.f, l2 = 0.f;
#pragma unroll
  for (int j = 0; j < 4; ++j) {
    half_t hh = (half_t)xs[j];
    float lf = xs[j] - (float)hh;
    hv[j] = hh;
    h2 += (float)hh * (float)hh;
    l2 += lf * lf;
  }
  const int tile = row >> 7, r = row & 127, kg = lane >> 1, off = (lane & 1) * 4;
  *(half4v*)(zh + (size_t)tile * 32768 + kg * 1024 + r * 8 + off) = hv;
#pragma unroll
  for (int o = 32; o > 0; o >>= 1) {
    h2 += __shfl_down(h2, o);
    l2 += __shfl_down(l2, o);
  }
  if (lane == 0) {
    znh[row] = sqrtf(h2);
    znl[row] = sqrtf(l2);
  }
}

// pack e hi-half into [ctile64][kg32][row%64][8] + fp32 ||e||^2 + max norms
__global__ __launch_bounds__(256) void k_prep_e(const float* __restrict__ e,
                                                half_t* __restrict__ eh,
                                                float* __restrict__ enorm,
                                                u32* __restrict__ Wb) {
  const int wid = threadIdx.x >> 6, lane = threadIdx.x & 63;
  const int row = blockIdx.x * 4 + wid;
  float4 v = *(const float4*)(e + (size_t)row * DN + lane * 4);
  float xs[4] = {v.x, v.y, v.z, v.w};
  half4v hv;
  float h2 = 0.f, l2 = 0.f, x2 = 0.f;
#pragma unroll
  for (int j = 0; j < 4; ++j) {
    half_t hh = (half_t)xs[j];
    float lf = xs[j] - (float)hh;
    hv[j] = hh;
    h2 += (float)hh * (float)hh;
    l2 += lf * lf;
    x2 += xs[j] * xs[j];
  }
  const int tile = row >> 6, r = row & 63, kg = lane >> 1, off = (lane & 1) * 4;
  *(half4v*)(eh + (size_t)tile * 16384 + kg * 512 + r * 8 + off) = hv;
#pragma unroll
  for (int o = 32; o > 0; o >>= 1) {
    h2 += __shfl_down(h2, o);
    l2 += __shfl_down(l2, o);
    x2 += __shfl_down(x2, o);
  }
  if (lane == 0) {
    enorm[row] = x2;
    atomicMax(Wb + 4, __float_as_uint(sqrtf(h2)));
    atomicMax(Wb + 5, __float_as_uint(sqrtf(l2)));
  }
}

// Block-local prune+refine argmin. Block = 128 z-rows x 2048-code split.
// (unchanged from round 6 -- known good)
__global__ __launch_bounds__(256, 2) void k_pass1(
    const half_t* __restrict__ eh, const half_t* __restrict__ zh,
    const float* __restrict__ z, const float* __restrict__ emb,
    const float* __restrict__ enorm, const float* __restrict__ znh,
    const float* __restrict__ znl, const float* __restrict__ Wf,
    u64* __restrict__ best, u32* __restrict__ oflow) {
  __shared__ __align__(16) half_t EB[2][8192];  // dbuf, [kg16][row64][8]
  __shared__ float En_s[2048];
  __shared__ u64 clist[128 * CCAP];
  __shared__ u32 pcnt[128];
  __shared__ float rowbest[128];

  const int tid = threadIdx.x;
  const int wid = tid >> 6, lane = tid & 63;
  const int l31 = lane & 31, h = lane >> 5;
  const int zt = blockIdx.x;   // z-tile (128 rows)
  const int sp = blockIdx.y;   // code split (2048 codes)
  const int lrow = wid * 32 + l31;   // block-local z-row owned by this lane
  const int grow = zt * 128 + lrow;  // global z-row

  for (int i = tid; i < 2048; i += 256) En_s[i] = enorm[sp * 2048 + i];
  if (tid < 128) pcnt[tid] = 0;

  // z fragments -> registers (kg = ks*2 + h), 16 x half8 = 64 VGPRs
  half8 zr[16];
  {
    const half_t* zb = zh + (size_t)zt * 32768 + (size_t)lrow * 8;
#pragma unroll
    for (int ks = 0; ks < 16; ++ks)
      zr[ks] = *(const half8*)(zb + (size_t)(ks * 2 + h) * 1024);
  }
  // rigorous hh->exact margin (2M + slack)
  const float thr2 =
      4.0f * (znh[grow] * Wf[5] + znl[grow] * (Wf[4] + Wf[5])) + 0.06f;

  const half_t* ebase = eh + ((size_t)sp << 19);  // split base: 32 ctiles
  float bestd = 3.4e38f;

#define STG(s, b)                                                              \
  {                                                                            \
    const half_t* g_ = ebase + (size_t)(s) * 8192 + wid * 2048 + lane * 8;     \
    half_t* d_ = &EB[b][wid * 2048 + lane * 8];                                \
    _Pragma("unroll") for (int i_ = 0; i_ < 4; ++i_)                           \
        __builtin_amdgcn_global_load_lds(                                      \
            (const __attribute__((address_space(1))) void*)(g_ + i_ * 512),    \
            (__attribute__((address_space(3))) void*)(d_ + i_ * 512), 16, 0,   \
            0);                                                                \
  }

  STG(0, 0)
  for (int t = 0; t < 32; ++t) {  // 32 code-tiles of 64
    float16v acc0 = {}, acc1 = {};
#pragma unroll
    for (int kh = 0; kh < 2; ++kh) {
      const int s = t * 2 + kh;
      __syncthreads();
      if (s < 63) STG(s + 1, (s + 1) & 1)
      const half_t* B = EB[s & 1];
#pragma unroll
      for (int ks = 0; ks < 8; ++ks) {
        const int ko = (ks * 2 + h) * 512;
        half8 a0 = *(const half8*)(B + ko + l31 * 8);
        half8 a1 = *(const half8*)(B + ko + (32 + l31) * 8);
        acc0 = __builtin_amdgcn_mfma_f32_32x32x16_f16(a0, zr[kh * 8 + ks],
                                                      acc0, 0, 0, 0);
        acc1 = __builtin_amdgcn_mfma_f32_32x32x16_f16(a1, zr[kh * 8 + ks],
                                                      acc1, 0, 0, 0);
      }
    }
    // epilogue pass 1: distances + tile min (col(z)=l31 -> row `grow`)
    float ds[32];
    float tmin = 3.4e38f;
#pragma unroll
    for (int mi = 0; mi < 2; ++mi) {
      const float16v a = mi ? acc1 : acc0;
#pragma unroll
      for (int r = 0; r < 16; ++r) {
        const int cl = t * 64 + mi * 32 + (r & 3) + 8 * (r >> 2) + 4 * h;
        const float d = En_s[cl] - 2.0f * a[r];
        ds[mi * 16 + r] = d;
        tmin = d < tmin ? d : tmin;
      }
    }
    {  // share tile-min across the h-pair, update running best
      float o = __shfl_xor(tmin, 32);
      tmin = o < tmin ? o : tmin;
      bestd = tmin < bestd ? tmin : bestd;
    }
    // epilogue pass 2: append candidates within margin of running best
    const float lim = bestd + thr2;
#pragma unroll
    for (int mi = 0; mi < 2; ++mi)
#pragma unroll
      for (int r = 0; r < 16; ++r) {
        const float d = ds[mi * 16 + r];
        if (d <= lim) {
          const int cl = t * 64 + mi * 32 + (r & 3) + 8 * (r >> 2) + 4 * h;
          const u32 slot = atomicAdd(&pcnt[lrow], 1u);
          if (slot < CCAP)
            clist[lrow * CCAP + slot] =
                ((u64)enc_f(d) << 32) | (u32)(sp * 2048 + cl);
        }
      }
  }
#undef STG

  if (h == 0) rowbest[lrow] = bestd;  // both h-lanes hold the same value
  __syncthreads();

  // Phase B: dh-filtered exact fp32 refine, wave-per-row
  for (int lr = wid; lr < 128; lr += 4) {
    const int gr = zt * 128 + lr;
    const u32 n = pcnt[lr];
    if (n > CCAP) {
      if (lane == 0) oflow[gr] = 1u;  // k_out rescans this row exactly
      continue;
    }
    const float t2 =
        4.0f * (znh[gr] * Wf[5] + znl[gr] * (Wf[4] + Wf[5])) + 0.06f;
    const u32 lim = enc_f(rowbest[lr] + t2);
    u64 bk = ~0ull;
    const float4 zv = *(const float4*)(z + (size_t)gr * DN + lane * 4);
    for (u32 j = 0; j < n; ++j) {
      const u64 e = clist[lr * CCAP + j];
      if ((u32)(e >> 32) > lim) continue;  // wave-uniform
      const int c = (int)(e & 0x1FFFu);
      float4 ev = *(const float4*)(emb + (size_t)c * DN + lane * 4);
      float dot = wave_reduce_add(zv.x * ev.x + zv.y * ev.y + zv.z * ev.z +
                                  zv.w * ev.w);
      if (lane == 0) {
        const float d = enorm[c] - 2.0f * dot;
        const u64 kk = ((u64)enc_f(d) << 32) | (u32)c;
        bk = kk < bk ? kk : bk;
      }
    }
    if (lane == 0) atomicMin(best + gr, bk);
  }
}

// wave per row: resolve index (oflow -> exact rescan), z_q straight-through,
// loss, cluster histogram. NO embsum atomics (counting sort handles that).
__global__ __launch_bounds__(256) void k_out(const float* __restrict__ z,
                                             const float* __restrict__ emb,
                                             const float* __restrict__ enorm,
                                             const u64* __restrict__ best,
                                             const u32* __restrict__ oflow,
                                             float* __restrict__ out,
                                             float* __restrict__ W,
                                             float* __restrict__ cluster,
                                             int* __restrict__ idxp) {
  int wid = threadIdx.x >> 6, lane = threadIdx.x & 63;
  int row = blockIdx.x * 4 + wid;
  int d = lane << 2;
  float4 zv = *(const float4*)(z + (size_t)row * DN + d);
  int k;
  if (oflow[row] != 0u) {  // provably-safe exact rescan (~never runs)
    u64 bk = ~0ull;
    for (int c = 0; c < KN; ++c) {
      float4 ev = *(const float4*)(emb + (size_t)c * DN + d);
      float dot = wave_reduce_add(zv.x * ev.x + zv.y * ev.y + zv.z * ev.z +
                                  zv.w * ev.w);
      if (lane == 0) {
        const float dd = enorm[c] - 2.0f * dot;
        const u64 kk = ((u64)enc_f(dd) << 32) | (u32)c;
        bk = kk < bk ? kk : bk;
      }
    }
    int k0 = (int)((u32)bk & 0x1FFFu);
    k = __shfl(k0, 0);
  } else {
    k = (int)((u32)best[row] & 0x1FFFu);
  }
  float4 ev = *(const float4*)(emb + (size_t)k * DN + d);
  float4 df = make_float4(ev.x - zv.x, ev.y - zv.y, ev.z - zv.z, ev.w - zv.w);
  float4 st = make_float4(zv.x + df.x, zv.y + df.y, zv.z + df.z, zv.w + df.w);
  *(float4*)(out + (size_t)row * DN + d) = st;
  float sq = df.x * df.x + df.y * df.y + df.z * df.z + df.w * df.w;
  sq = wave_reduce_add(sq);
  if (lane == 0) {
    unsafeAtomicAdd(&W[0], sq);
    unsafeAtomicAdd(&cluster[k], 1.0f);
    out[O_IDX + row] = (float)k;
    idxp[row] = k;
  }
}

// single block: EMA cluster stats + exclusive prefix (for counting sort)
__global__ __launch_bounds__(256) void k_scan(const float* __restrict__ ema_cs,
                                              const float* __restrict__ cluster,
                                              float* __restrict__ newcs,
                                              int* __restrict__ rowstart,
                                              int* __restrict__ cursor,
                                              float* __restrict__ Wf) {
  __shared__ int ssum[256];
  __shared__ float sn[256], sp[256];
  const int t = threadIdx.x;
  const int base = t * 32;
  int s = 0;
  float nsum = 0.f, plsum = 0.f;
  for (int j = 0; j < 32; ++j) {
    float cs = cluster[base + j];
    s += (int)cs;
    float nc = 0.99f * ema_cs[base + j] + 0.01f * cs;
    newcs[base + j] = nc;
    nsum += nc;
    float p = cs * (1.0f / 32768.0f);
    plsum += p * logf(p + 1e-10f);
  }
  ssum[t] = s;
  sn[t] = nsum;
  sp[t] = plsum;
  __syncthreads();
  for (int st = 1; st < 256; st <<= 1) {  // Hillis-Steele inclusive scan
    int v = (t >= st) ? ssum[t - st] : 0;
    __syncthreads();
    ssum[t] += v;
    __syncthreads();
  }
  int off = ssum[t] - s;  // exclusive prefix
  for (int j = 0; j < 32; ++j) {
    rowstart[base + j] = off;
    cursor[base + j] = off;
    off += (int)cluster[base + j];
  }
  for (int st = 128; st > 0; st >>= 1) {
    if (t < st) {
      sn[t] += sn[t + st];
      sp[t] += sp[t + st];
    }
    __syncthreads();
  }
  if (t == 0) {
    Wf[1] = sn[0];
    Wf[2] = sp[0];
  }
}

__global__ __launch_bounds__(256) void k_scatter(const int* __restrict__ idxp,
                                                 int* __restrict__ cursor,
                                                 int* __restrict__ rowlist) {
  const int row = blockIdx.x * 256 + threadIdx.x;
  const int pos = atomicAdd(cursor + idxp[row], 1);
  rowlist[pos] = row;
}

// wave per code: segmented sum of z rows -> clean embsum writes (no atomics)
__global__ __launch_bounds__(256) void k_accum(const float* __restrict__ z,
                                               const float* __restrict__ cluster,
                                               const int* __restrict__ rowstart,
                                               const int* __restrict__ rowlist,
                                               float* __restrict__ embsum) {
  const int wid = threadIdx.x >> 6, lane = threadIdx.x & 63;
  const int code = blockIdx.x * 4 + wid;
  const int cnt = (int)cluster[code];
  const int st = rowstart[code];
  float4 a = make_float4(0.f, 0.f, 0.f, 0.f);
  for (int j = 0; j < cnt; ++j) {
    const int row = rowlist[st + j];
    float4 v = *(const float4*)(z + (size_t)row * DN + lane * 4);
    a.x += v.x;
    a.y += v.y;
    a.z += v.z;
    a.w += v.w;
  }
  *(float4*)(embsum + (size_t)code * DN + lane * 4) = a;
}

__global__ __launch_bounds__(256) void k_final(const float* __restrict__ z,
                                               const float* __restrict__ ema_es,
                                               const float* __restrict__ noise,
                                               const int* __restrict__ ridx,
                                               const float* __restrict__ embsum,
                                               const float* __restrict__ newcs,
                                               const float* __restrict__ W,
                                               float* __restrict__ out) {
  int gid = blockIdx.x * 256 + threadIdx.x;  // 0 .. KN*64-1
  int k = gid >> 6;
  int d = (gid & 63) << 2;
  float n = W[1];
  float nc = newcs[k];
  float cs_sm = (nc + 1e-5f) / (n + (float)KN * 1e-5f) * n;
  bool dead = (nc / n) < (1.0f / (KN * 10.0f));
  size_t o = (size_t)k * DN + d;
  float4 es = *(const float4*)(ema_es + o);
  float4 s = *(const float4*)(embsum + o);
  float4 nes = make_float4(0.99f * es.x + 0.01f * s.x, 0.99f * es.y + 0.01f * s.y,
                           0.99f * es.z + 0.01f * s.z, 0.99f * es.w + 0.01f * s.w);
  float4 ne = make_float4(nes.x / cs_sm, nes.y / cs_sm, nes.z / cs_sm,
                          nes.w / cs_sm);
  if (dead) {  // wave-uniform (one k per wave)
    int r = ridx[k];
    float4 rz = *(const float4*)(z + (size_t)r * DN + d);
    float4 rn = *(const float4*)(noise + o);
    nes = make_float4(rz.x + rn.x, rz.y + rn.y, rz.z + rn.z, rz.w + rn.w);
    ne = nes;
  }
  float* oe = out + O_EMB + o;  // 8B-aligned region -> float2 stores
  *(float2*)(oe) = make_float2(ne.x, ne.y);
  *(float2*)(oe + 2) = make_float2(ne.z, ne.w);
  float* os = out + O_ES + o;
  *(float2*)(os) = make_float2(nes.x, nes.y);
  *(float2*)(os + 2) = make_float2(nes.z, nes.w);
  if ((gid & 63) == 0) out[O_CS + k] = dead ? 1.0f : nc;
  if (gid == 0) {
    out[O_LOSS] = 0.25f * W[0] * (1.0f / 8388608.0f);
    out[O_PERP] = expf(-W[2]);
  }
}

extern "C" void kernel_launch(void* const* d_in, const int* in_sizes, int n_in,
                              void* d_out, int out_size, void* d_ws,
                              size_t ws_size, hipStream_t stream) {
  const float* z = (const float*)d_in[0];
  const float* emb = (const float*)d_in[1];
  const float* ema_cs = (const float*)d_in[2];
  const float* ema_es = (const float*)d_in[3];
  const float* noise = (const float*)d_in[4];
  const int* ridx = (const int*)d_in[5];
  float* out = (float*)d_out;

  // ws layout (floats unless noted): Wf[16] cluster[8K] oflow[32K u32]
  // newcs[8K] enorm[8K] znh[32K] znl[32K] rowstart[8K] cursor[8K]
  // rowlist[32K] idxp[32K] best[32K u64] embsum[2.1M]
  float* Wf = (float*)d_ws;
  float* cluster = Wf + 16;
  u32* oflow = (u32*)(cluster + KN);
  float* newcs = (float*)(oflow + BN);
  float* enorm = newcs + KN;
  float* znh = enorm + KN;
  float* znl = znh + BN;
  int* rowstart = (int*)(znl + BN);
  int* cursor = rowstart + KN;
  int* rowlist = cursor + KN;
  int* idxp = rowlist + BN;
  u64* best = (u64*)(idxp + BN);
  float* embsum = (float*)(best + BN);

  // packed-fp16 scratch in d_out's z_q region (overwritten by k_out later):
  // zh 16.8MB at [0, BN*DN/2), eh 4.2MB after it
  half_t* zh = (half_t*)out;
  half_t* eh = (half_t*)(out + (size_t)BN * DN / 2);

  // zero Wf + cluster + oflow (contiguous); embsum needs no zeroing
  // (k_accum writes every element cleanly)
  hipMemsetAsync(Wf, 0, (size_t)(16 + KN + BN) * sizeof(float), stream);
  hipMemsetAsync(best, 0xFF, (size_t)BN * sizeof(u64), stream);

  k_prep_z<<<BN / 4, 256, 0, stream>>>(z, zh, znh, znl);
  k_prep_e<<<KN / 4, 256, 0, stream>>>(emb, eh, enorm, (u32*)Wf);
  k_pass1<<<dim3(BN / 128, 4), 256, 0, stream>>>(eh, zh, z, emb, enorm, znh,
                                                 znl, Wf, best, oflow);
  k_out<<<BN / 4, 256, 0, stream>>>(z, emb, enorm, best, oflow, out, Wf,
                                    cluster, idxp);
  k_scan<<<1, 256, 0, stream>>>(ema_cs, cluster, newcs, rowstart, cursor, Wf);
  k_scatter<<<BN / 256, 256, 0, stream>>>(idxp, cursor, rowlist);
  k_accum<<<KN / 4, 256, 0, stream>>>(z, cluster, rowstart, rowlist, embsum);
  k_final<<<(KN * 64) / 256, 256, 0, stream>>>(z, ema_es, noise, ridx, embsum,
                                               newcs, Wf, out);
}

// Round 8
// 637.076 us; speedup vs baseline: 1.9264x; 1.9264x over previous
//
#include <hip/hip_runtime.h>
#include <math.h>

#define BN 32768
#define DN 256
#define KN 8192
#define CCAP 20

// Output layout (floats, concatenated in reference return order)
#define O_LOSS 8388608       // BN*DN
#define O_IDX  8388609
#define O_PERP 8421377       // O_IDX + BN
#define O_EMB  8421378
#define O_CS   10518530      // O_EMB + KN*DN
#define O_ES   10526722      // O_CS + KN

typedef _Float16 half_t;
typedef __attribute__((ext_vector_type(4))) _Float16 half4v;
typedef __attribute__((ext_vector_type(8))) _Float16 half8;
typedef __attribute__((ext_vector_type(16))) float float16v;
typedef unsigned long long u64;
typedef unsigned int u32;

__device__ __forceinline__ float wave_reduce_add(float v) {
#pragma unroll
  for (int off = 32; off > 0; off >>= 1) v += __shfl_down(v, off);
  return v;
}

__device__ __forceinline__ u32 enc_f(float d) {
  u32 fb = __float_as_uint(d);
  return fb ^ ((fb >> 31) ? 0xFFFFFFFFu : 0x80000000u);
}

// pack z hi-half into [ztile128][kg32][row%128][8] + hi/lo norms per row
__global__ __launch_bounds__(256) void k_prep_z(const float* __restrict__ z,
                                                half_t* __restrict__ zh,
                                                float* __restrict__ znh,
                                                float* __restrict__ znl) {
  const int wid = threadIdx.x >> 6, lane = threadIdx.x & 63;
  const int row = blockIdx.x * 4 + wid;
  float4 v = *(const float4*)(z + (size_t)row * DN + lane * 4);
  float xs[4] = {v.x, v.y, v.z, v.w};
  half4v hv;
  float h2 = 0.f, l2 = 0.f;
#pragma unroll
  for (int j = 0; j < 4; ++j) {
    half_t hh = (half_t)xs[j];
    float lf = xs[j] - (float)hh;
    hv[j] = hh;
    h2 += (float)hh * (float)hh;
    l2 += lf * lf;
  }
  const int tile = row >> 7, r = row & 127, kg = lane >> 1, off = (lane & 1) * 4;
  *(half4v*)(zh + (size_t)tile * 32768 + kg * 1024 + r * 8 + off) = hv;
#pragma unroll
  for (int o = 32; o > 0; o >>= 1) {
    h2 += __shfl_down(h2, o);
    l2 += __shfl_down(l2, o);
  }
  if (lane == 0) {
    znh[row] = sqrtf(h2);
    znl[row] = sqrtf(l2);
  }
}

// pack e hi-half into [ctile64][kg32][row%64][8] + fp32 ||e||^2.
// per-block max norms -> clean stores (NO single-address atomics).
__global__ __launch_bounds__(256) void k_prep_e(const float* __restrict__ e,
                                                half_t* __restrict__ eh,
                                                float* __restrict__ enorm,
                                                float* __restrict__ emaxp) {
  __shared__ float mh[4], ml[4];
  const int wid = threadIdx.x >> 6, lane = threadIdx.x & 63;
  const int row = blockIdx.x * 4 + wid;
  float4 v = *(const float4*)(e + (size_t)row * DN + lane * 4);
  float xs[4] = {v.x, v.y, v.z, v.w};
  half4v hv;
  float h2 = 0.f, l2 = 0.f, x2 = 0.f;
#pragma unroll
  for (int j = 0; j < 4; ++j) {
    half_t hh = (half_t)xs[j];
    float lf = xs[j] - (float)hh;
    hv[j] = hh;
    h2 += (float)hh * (float)hh;
    l2 += lf * lf;
    x2 += xs[j] * xs[j];
  }
  const int tile = row >> 6, r = row & 63, kg = lane >> 1, off = (lane & 1) * 4;
  *(half4v*)(eh + (size_t)tile * 16384 + kg * 512 + r * 8 + off) = hv;
#pragma unroll
  for (int o = 32; o > 0; o >>= 1) {
    h2 += __shfl_down(h2, o);
    l2 += __shfl_down(l2, o);
    x2 += __shfl_down(x2, o);
  }
  if (lane == 0) {
    enorm[row] = x2;
    mh[wid] = sqrtf(h2);
    ml[wid] = sqrtf(l2);
  }
  __syncthreads();
  if (threadIdx.x == 0) {
    emaxp[blockIdx.x * 2] = fmaxf(fmaxf(mh[0], mh[1]), fmaxf(mh[2], mh[3]));
    emaxp[blockIdx.x * 2 + 1] = fmaxf(fmaxf(ml[0], ml[1]), fmaxf(ml[2], ml[3]));
  }
}

// single block: fold 2048 per-block norm maxima -> Wf[4], Wf[5]
__global__ __launch_bounds__(256) void k_norm(const float* __restrict__ emaxp,
                                              float* __restrict__ Wf) {
  __shared__ float sh[256], sl[256];
  const int t = threadIdx.x;
  float vh = 0.f, vl = 0.f;
  for (int i = t; i < 2048; i += 256) {
    vh = fmaxf(vh, emaxp[i * 2]);
    vl = fmaxf(vl, emaxp[i * 2 + 1]);
  }
  sh[t] = vh;
  sl[t] = vl;
  __syncthreads();
  for (int st = 128; st > 0; st >>= 1) {
    if (t < st) {
      sh[t] = fmaxf(sh[t], sh[t + st]);
      sl[t] = fmaxf(sl[t], sl[t + st]);
    }
    __syncthreads();
  }
  if (t == 0) {
    Wf[4] = sh[0];
    Wf[5] = sl[0];
  }
}

// Block-local prune+refine argmin. Block = 128 z-rows x 2048-code split.
// (unchanged -- known good)
__global__ __launch_bounds__(256, 2) void k_pass1(
    const half_t* __restrict__ eh, const half_t* __restrict__ zh,
    const float* __restrict__ z, const float* __restrict__ emb,
    const float* __restrict__ enorm, const float* __restrict__ znh,
    const float* __restrict__ znl, const float* __restrict__ Wf,
    u64* __restrict__ best, u32* __restrict__ oflow) {
  __shared__ __align__(16) half_t EB[2][8192];  // dbuf, [kg16][row64][8]
  __shared__ float En_s[2048];
  __shared__ u64 clist[128 * CCAP];
  __shared__ u32 pcnt[128];
  __shared__ float rowbest[128];

  const int tid = threadIdx.x;
  const int wid = tid >> 6, lane = tid & 63;
  const int l31 = lane & 31, h = lane >> 5;
  const int zt = blockIdx.x;   // z-tile (128 rows)
  const int sp = blockIdx.y;   // code split (2048 codes)
  const int lrow = wid * 32 + l31;   // block-local z-row owned by this lane
  const int grow = zt * 128 + lrow;  // global z-row

  for (int i = tid; i < 2048; i += 256) En_s[i] = enorm[sp * 2048 + i];
  if (tid < 128) pcnt[tid] = 0;

  // z fragments -> registers (kg = ks*2 + h), 16 x half8 = 64 VGPRs
  half8 zr[16];
  {
    const half_t* zb = zh + (size_t)zt * 32768 + (size_t)lrow * 8;
#pragma unroll
    for (int ks = 0; ks < 16; ++ks)
      zr[ks] = *(const half8*)(zb + (size_t)(ks * 2 + h) * 1024);
  }
  // rigorous hh->exact margin (2M + slack)
  const float thr2 =
      4.0f * (znh[grow] * Wf[5] + znl[grow] * (Wf[4] + Wf[5])) + 0.06f;

  const half_t* ebase = eh + ((size_t)sp << 19);  // split base: 32 ctiles
  float bestd = 3.4e38f;

#define STG(s, b)                                                              \
  {                                                                            \
    const half_t* g_ = ebase + (size_t)(s) * 8192 + wid * 2048 + lane * 8;     \
    half_t* d_ = &EB[b][wid * 2048 + lane * 8];                                \
    _Pragma("unroll") for (int i_ = 0; i_ < 4; ++i_)                           \
        __builtin_amdgcn_global_load_lds(                                      \
            (const __attribute__((address_space(1))) void*)(g_ + i_ * 512),    \
            (__attribute__((address_space(3))) void*)(d_ + i_ * 512), 16, 0,   \
            0);                                                                \
  }

  STG(0, 0)
  for (int t = 0; t < 32; ++t) {  // 32 code-tiles of 64
    float16v acc0 = {}, acc1 = {};
#pragma unroll
    for (int kh = 0; kh < 2; ++kh) {
      const int s = t * 2 + kh;
      __syncthreads();
      if (s < 63) STG(s + 1, (s + 1) & 1)
      const half_t* B = EB[s & 1];
#pragma unroll
      for (int ks = 0; ks < 8; ++ks) {
        const int ko = (ks * 2 + h) * 512;
        half8 a0 = *(const half8*)(B + ko + l31 * 8);
        half8 a1 = *(const half8*)(B + ko + (32 + l31) * 8);
        acc0 = __builtin_amdgcn_mfma_f32_32x32x16_f16(a0, zr[kh * 8 + ks],
                                                      acc0, 0, 0, 0);
        acc1 = __builtin_amdgcn_mfma_f32_32x32x16_f16(a1, zr[kh * 8 + ks],
                                                      acc1, 0, 0, 0);
      }
    }
    // epilogue pass 1: distances + tile min (col(z)=l31 -> row `grow`)
    float ds[32];
    float tmin = 3.4e38f;
#pragma unroll
    for (int mi = 0; mi < 2; ++mi) {
      const float16v a = mi ? acc1 : acc0;
#pragma unroll
      for (int r = 0; r < 16; ++r) {
        const int cl = t * 64 + mi * 32 + (r & 3) + 8 * (r >> 2) + 4 * h;
        const float d = En_s[cl] - 2.0f * a[r];
        ds[mi * 16 + r] = d;
        tmin = d < tmin ? d : tmin;
      }
    }
    {  // share tile-min across the h-pair, update running best
      float o = __shfl_xor(tmin, 32);
      tmin = o < tmin ? o : tmin;
      bestd = tmin < bestd ? tmin : bestd;
    }
    // epilogue pass 2: append candidates within margin of running best
    const float lim = bestd + thr2;
#pragma unroll
    for (int mi = 0; mi < 2; ++mi)
#pragma unroll
      for (int r = 0; r < 16; ++r) {
        const float d = ds[mi * 16 + r];
        if (d <= lim) {
          const int cl = t * 64 + mi * 32 + (r & 3) + 8 * (r >> 2) + 4 * h;
          const u32 slot = atomicAdd(&pcnt[lrow], 1u);
          if (slot < CCAP)
            clist[lrow * CCAP + slot] =
                ((u64)enc_f(d) << 32) | (u32)(sp * 2048 + cl);
        }
      }
  }
#undef STG

  if (h == 0) rowbest[lrow] = bestd;  // both h-lanes hold the same value
  __syncthreads();

  // Phase B: dh-filtered exact fp32 refine, wave-per-row
  for (int lr = wid; lr < 128; lr += 4) {
    const int gr = zt * 128 + lr;
    const u32 n = pcnt[lr];
    if (n > CCAP) {
      if (lane == 0) oflow[gr] = 1u;  // k_out rescans this row exactly
      continue;
    }
    const float t2 =
        4.0f * (znh[gr] * Wf[5] + znl[gr] * (Wf[4] + Wf[5])) + 0.06f;
    const u32 lim = enc_f(rowbest[lr] + t2);
    u64 bk = ~0ull;
    const float4 zv = *(const float4*)(z + (size_t)gr * DN + lane * 4);
    for (u32 j = 0; j < n; ++j) {
      const u64 e = clist[lr * CCAP + j];
      if ((u32)(e >> 32) > lim) continue;  // wave-uniform
      const int c = (int)(e & 0x1FFFu);
      float4 ev = *(const float4*)(emb + (size_t)c * DN + lane * 4);
      float dot = wave_reduce_add(zv.x * ev.x + zv.y * ev.y + zv.z * ev.z +
                                  zv.w * ev.w);
      if (lane == 0) {
        const float d = enorm[c] - 2.0f * dot;
        const u64 kk = ((u64)enc_f(d) << 32) | (u32)c;
        bk = kk < bk ? kk : bk;
      }
    }
    if (lane == 0) atomicMin(best + gr, bk);
  }
}

// wave per row: resolve index (oflow -> exact rescan), z_q straight-through,
// cluster histogram. Loss partial -> clean per-block store (NO W[0] atomic).
__global__ __launch_bounds__(256) void k_out(const float* __restrict__ z,
                                             const float* __restrict__ emb,
                                             const float* __restrict__ enorm,
                                             const u64* __restrict__ best,
                                             const u32* __restrict__ oflow,
                                             float* __restrict__ out,
                                             float* __restrict__ losspart,
                                             float* __restrict__ cluster,
                                             int* __restrict__ idxp) {
  __shared__ float lp[4];
  int wid = threadIdx.x >> 6, lane = threadIdx.x & 63;
  int row = blockIdx.x * 4 + wid;
  int d = lane << 2;
  float4 zv = *(const float4*)(z + (size_t)row * DN + d);
  int k;
  if (oflow[row] != 0u) {  // provably-safe exact rescan (~never runs)
    u64 bk = ~0ull;
    for (int c = 0; c < KN; ++c) {
      float4 ev = *(const float4*)(emb + (size_t)c * DN + d);
      float dot = wave_reduce_add(zv.x * ev.x + zv.y * ev.y + zv.z * ev.z +
                                  zv.w * ev.w);
      if (lane == 0) {
        const float dd = enorm[c] - 2.0f * dot;
        const u64 kk = ((u64)enc_f(dd) << 32) | (u32)c;
        bk = kk < bk ? kk : bk;
      }
    }
    int k0 = (int)((u32)bk & 0x1FFFu);
    k = __shfl(k0, 0);
  } else {
    k = (int)((u32)best[row] & 0x1FFFu);
  }
  float4 ev = *(const float4*)(emb + (size_t)k * DN + d);
  float4 df = make_float4(ev.x - zv.x, ev.y - zv.y, ev.z - zv.z, ev.w - zv.w);
  float4 st = make_float4(zv.x + df.x, zv.y + df.y, zv.z + df.z, zv.w + df.w);
  *(float4*)(out + (size_t)row * DN + d) = st;
  float sq = df.x * df.x + df.y * df.y + df.z * df.z + df.w * df.w;
  sq = wave_reduce_add(sq);
  if (lane == 0) {
    lp[wid] = sq;
    unsafeAtomicAdd(&cluster[k], 1.0f);  // spread over 8192 addrs: pipelined
    out[O_IDX + row] = (float)k;
    idxp[row] = k;
  }
  __syncthreads();
  if (threadIdx.x == 0)
    losspart[blockIdx.x] = lp[0] + lp[1] + lp[2] + lp[3];
}

// single block: EMA cluster stats + exclusive prefix + loss-partial fold
__global__ __launch_bounds__(256) void k_scan(const float* __restrict__ ema_cs,
                                              const float* __restrict__ cluster,
                                              const float* __restrict__ losspart,
                                              float* __restrict__ newcs,
                                              int* __restrict__ rowstart,
                                              int* __restrict__ cursor,
                                              float* __restrict__ Wf) {
  __shared__ int ssum[256];
  __shared__ float sn[256], sp[256], sl[256];
  const int t = threadIdx.x;
  const int base = t * 32;
  int s = 0;
  float nsum = 0.f, plsum = 0.f, lsum = 0.f;
  for (int j = 0; j < 32; ++j) {
    float cs = cluster[base + j];
    s += (int)cs;
    float nc = 0.99f * ema_cs[base + j] + 0.01f * cs;
    newcs[base + j] = nc;
    nsum += nc;
    float p = cs * (1.0f / 32768.0f);
    plsum += p * logf(p + 1e-10f);
    lsum += losspart[base + j];
  }
  ssum[t] = s;
  sn[t] = nsum;
  sp[t] = plsum;
  sl[t] = lsum;
  __syncthreads();
  for (int st = 1; st < 256; st <<= 1) {  // Hillis-Steele inclusive scan
    int v = (t >= st) ? ssum[t - st] : 0;
    __syncthreads();
    ssum[t] += v;
    __syncthreads();
  }
  int off = ssum[t] - s;  // exclusive prefix
  for (int j = 0; j < 32; ++j) {
    rowstart[base + j] = off;
    cursor[base + j] = off;
    off += (int)cluster[base + j];
  }
  for (int st = 128; st > 0; st >>= 1) {
    if (t < st) {
      sn[t] += sn[t + st];
      sp[t] += sp[t + st];
      sl[t] += sl[t + st];
    }
    __syncthreads();
  }
  if (t == 0) {
    Wf[0] = sl[0];
    Wf[1] = sn[0];
    Wf[2] = sp[0];
  }
}

__global__ __launch_bounds__(256) void k_scatter(const int* __restrict__ idxp,
                                                 int* __restrict__ cursor,
                                                 int* __restrict__ rowlist) {
  const int row = blockIdx.x * 256 + threadIdx.x;
  const int pos = atomicAdd(cursor + idxp[row], 1);
  rowlist[pos] = row;
}

// wave per code: segmented sum of z rows -> clean embsum writes (no atomics)
__global__ __launch_bounds__(256) void k_accum(const float* __restrict__ z,
                                               const float* __restrict__ cluster,
                                               const int* __restrict__ rowstart,
                                               const int* __restrict__ rowlist,
                                               float* __restrict__ embsum) {
  const int wid = threadIdx.x >> 6, lane = threadIdx.x & 63;
  const int code = blockIdx.x * 4 + wid;
  const int cnt = (int)cluster[code];
  const int st = rowstart[code];
  float4 a = make_float4(0.f, 0.f, 0.f, 0.f);
  for (int j = 0; j < cnt; ++j) {
    const int row = rowlist[st + j];
    float4 v = *(const float4*)(z + (size_t)row * DN + lane * 4);
    a.x += v.x;
    a.y += v.y;
    a.z += v.z;
    a.w += v.w;
  }
  *(float4*)(embsum + (size_t)code * DN + lane * 4) = a;
}

__global__ __launch_bounds__(256) void k_final(const float* __restrict__ z,
                                               const float* __restrict__ ema_es,
                                               const float* __restrict__ noise,
                                               const int* __restrict__ ridx,
                                               const float* __restrict__ embsum,
                                               const float* __restrict__ newcs,
                                               const float* __restrict__ W,
                                               float* __restrict__ out) {
  int gid = blockIdx.x * 256 + threadIdx.x;  // 0 .. KN*64-1
  int k = gid >> 6;
  int d = (gid & 63) << 2;
  float n = W[1];
  float nc = newcs[k];
  float cs_sm = (nc + 1e-5f) / (n + (float)KN * 1e-5f) * n;
  bool dead = (nc / n) < (1.0f / (KN * 10.0f));
  size_t o = (size_t)k * DN + d;
  float4 es = *(const float4*)(ema_es + o);
  float4 s = *(const float4*)(embsum + o);
  float4 nes = make_float4(0.99f * es.x + 0.01f * s.x, 0.99f * es.y + 0.01f * s.y,
                           0.99f * es.z + 0.01f * s.z, 0.99f * es.w + 0.01f * s.w);
  float4 ne = make_float4(nes.x / cs_sm, nes.y / cs_sm, nes.z / cs_sm,
                          nes.w / cs_sm);
  if (dead) {  // wave-uniform (one k per wave)
    int r = ridx[k];
    float4 rz = *(const float4*)(z + (size_t)r * DN + d);
    float4 rn = *(const float4*)(noise + o);
    nes = make_float4(rz.x + rn.x, rz.y + rn.y, rz.z + rn.z, rz.w + rn.w);
    ne = nes;
  }
  float* oe = out + O_EMB + o;  // 8B-aligned region -> float2 stores
  *(float2*)(oe) = make_float2(ne.x, ne.y);
  *(float2*)(oe + 2) = make_float2(ne.z, ne.w);
  float* os = out + O_ES + o;
  *(float2*)(os) = make_float2(nes.x, nes.y);
  *(float2*)(os + 2) = make_float2(nes.z, nes.w);
  if ((gid & 63) == 0) out[O_CS + k] = dead ? 1.0f : nc;
  if (gid == 0) {
    out[O_LOSS] = 0.25f * W[0] * (1.0f / 8388608.0f);
    out[O_PERP] = expf(-W[2]);
  }
}

extern "C" void kernel_launch(void* const* d_in, const int* in_sizes, int n_in,
                              void* d_out, int out_size, void* d_ws,
                              size_t ws_size, hipStream_t stream) {
  const float* z = (const float*)d_in[0];
  const float* emb = (const float*)d_in[1];
  const float* ema_cs = (const float*)d_in[2];
  const float* ema_es = (const float*)d_in[3];
  const float* noise = (const float*)d_in[4];
  const int* ridx = (const int*)d_in[5];
  float* out = (float*)d_out;

  // ws layout (floats unless noted): Wf[16] cluster[8K] oflow[32K u32]
  // newcs[8K] enorm[8K] znh[32K] znl[32K] rowstart[8K] cursor[8K]
  // rowlist[32K] idxp[32K] losspart[8K] emaxp[4K] best[32K u64] embsum[2.1M]
  float* Wf = (float*)d_ws;
  float* cluster = Wf + 16;
  u32* oflow = (u32*)(cluster + KN);
  float* newcs = (float*)(oflow + BN);
  float* enorm = newcs + KN;
  float* znh = enorm + KN;
  float* znl = znh + BN;
  int* rowstart = (int*)(znl + BN);
  int* cursor = rowstart + KN;
  int* rowlist = cursor + KN;
  int* idxp = rowlist + BN;
  float* losspart = (float*)(idxp + BN);
  float* emaxp = losspart + KN;
  u64* best = (u64*)(emaxp + 4096);
  float* embsum = (float*)(best + BN);

  // packed-fp16 scratch in d_out's z_q region (overwritten by k_out later):
  // zh 16.8MB at [0, BN*DN/2), eh 4.2MB after it
  half_t* zh = (half_t*)out;
  half_t* eh = (half_t*)(out + (size_t)BN * DN / 2);

  // zero Wf + cluster + oflow (contiguous); losspart/emaxp/embsum are
  // written cleanly before read
  hipMemsetAsync(Wf, 0, (size_t)(16 + KN + BN) * sizeof(float), stream);
  hipMemsetAsync(best, 0xFF, (size_t)BN * sizeof(u64), stream);

  k_prep_z<<<BN / 4, 256, 0, stream>>>(z, zh, znh, znl);
  k_prep_e<<<KN / 4, 256, 0, stream>>>(emb, eh, enorm, emaxp);
  k_norm<<<1, 256, 0, stream>>>(emaxp, Wf);
  k_pass1<<<dim3(BN / 128, 4), 256, 0, stream>>>(eh, zh, z, emb, enorm, znh,
                                                 znl, Wf, best, oflow);
  k_out<<<BN / 4, 256, 0, stream>>>(z, emb, enorm, best, oflow, out, losspart,
                                    cluster, idxp);
  k_scan<<<1, 256, 0, stream>>>(ema_cs, cluster, losspart, newcs, rowstart,
                                cursor, Wf);
  k_scatter<<<BN / 256, 256, 0, stream>>>(idxp, cursor, rowlist);
  k_accum<<<KN / 4, 256, 0, stream>>>(z, cluster, rowstart, rowlist, embsum);
  k_final<<<(KN * 64) / 256, 256, 0, stream>>>(z, ema_es, noise, ridx, embsum,
                                               newcs, Wf, out);
}